// Round 11
// baseline (408.481 us; speedup 1.0000x reference)
//
#include <hip/hip_runtime.h>
#include <cstdint>
#include <cstddef>

#define S_LEN 2048
#define D_MODEL 2048
#define NH 32
#define NKV 8
#define HD_ 64
#define BATCH 2
#define KVD 512
#define MTOT 4096
#define QSC 0.18033688011112042f   // 0.125 * log2(e): QK^T lands in exp2 domain

typedef float f32x4 __attribute__((ext_vector_type(4)));
typedef short s16x8 __attribute__((ext_vector_type(8)));
typedef unsigned int u32;
typedef unsigned int u32x4 __attribute__((ext_vector_type(4)));

__device__ __forceinline__ unsigned short f2bf(float f) {
  unsigned int u = __builtin_bit_cast(unsigned int, f);
  u = (u + 0x7fffu + ((u >> 16) & 1u)) >> 16;
  return (unsigned short)u;
}
__device__ __forceinline__ float bf2f(unsigned short h) {
  return __builtin_bit_cast(float, ((unsigned int)h) << 16);
}
__device__ __forceinline__ float fexp2(float x) {
#if __has_builtin(__builtin_amdgcn_exp2f)
  return __builtin_amdgcn_exp2f(x);
#else
  return exp2f(x);
#endif
}

// async global->LDS, 16B per lane; LDS dest = wave-uniform base + lane*16 (linear only)
__device__ __forceinline__ void gl_lds16(const void* g, void* l) {
  __builtin_amdgcn_global_load_lds((const __attribute__((address_space(1))) u32*)g,
                                   (__attribute__((address_space(3))) u32*)l, 16, 0, 0);
}

// ---------------- fused 5-tensor f32 -> bf16 convert ----------------
__global__ void cvt5_kernel(const float* __restrict__ x, const float* __restrict__ a,
                            const float* __restrict__ b, const float* __restrict__ c,
                            const float* __restrict__ d,
                            unsigned short* __restrict__ ox, unsigned short* __restrict__ oa,
                            unsigned short* __restrict__ ob, unsigned short* __restrict__ oc,
                            unsigned short* __restrict__ od,
                            int nx4, int na4, int nb4, int nc4, int nd4) {
  int j = blockIdx.x * blockDim.x + threadIdx.x;
  const float* src; unsigned short* dst;
  if (j < nx4) { src = x; dst = ox; }
  else {
    j -= nx4;
    if (j < na4) { src = a; dst = oa; }
    else {
      j -= na4;
      if (j < nb4) { src = b; dst = ob; }
      else {
        j -= nb4;
        if (j < nc4) { src = c; dst = oc; }
        else {
          j -= nc4;
          if (j >= nd4) return;
          src = d; dst = od;
        }
      }
    }
  }
  float4 v = reinterpret_cast<const float4*>(src)[j];
  ushort4 o;
  o.x = f2bf(v.x); o.y = f2bf(v.y); o.z = f2bf(v.z); o.w = f2bf(v.w);
  reinterpret_cast<ushort4*>(dst)[j] = o;
}

// ---------------- fused QKV projection with RoPE epilogue ----------------
// m97 structure: 128x128 tile, BK=32, global_load_lds w16, LINEAR LDS.
// blockIdx.x: 0..15 -> Q (RoPE + QSC scale), 16..19 -> K (RoPE), 20..23 -> V (transposed out).
__global__ __launch_bounds__(256) void gemm_qkv(const unsigned short* __restrict__ A,
                                                const unsigned short* __restrict__ Wq,
                                                const unsigned short* __restrict__ Wk,
                                                const unsigned short* __restrict__ Wv,
                                                const float* __restrict__ cosb,
                                                const float* __restrict__ sinb,
                                                unsigned short* __restrict__ Cq,
                                                unsigned short* __restrict__ Ck,
                                                unsigned short* __restrict__ Cvt,
                                                int M, int K) {
  __shared__ alignas(16) short As[128 * 32];
  __shared__ alignas(16) short Bs[128 * 32];
  int tid = threadIdx.x;
  int lane = tid & 63, wid = tid >> 6;
  int bx = blockIdx.x;
  const unsigned short* W; int n0, mode;
  if (bx < 16)      { W = Wq; n0 = bx * 128;        mode = 0; }
  else if (bx < 20) { W = Wk; n0 = (bx - 16) * 128; mode = 1; }
  else              { W = Wv; n0 = (bx - 20) * 128; mode = 2; }
  int m0 = blockIdx.y * 128;
  int wm = (wid >> 1) * 64, wn = (wid & 1) * 64;
  int lrow = lane & 15, lkk = lane >> 4;
  int srow = lane >> 2;
  int scb  = (lane & 3) * 16;
  f32x4 acc[4][4] = {};

  for (int k0 = 0; k0 < K; k0 += 32) {
    __syncthreads();
#pragma unroll
    for (int i = 0; i < 2; ++i) {
      int c = wid * 2 + i;
      int row = c * 16 + srow;
      const char* ga = (const char*)A + ((size_t)(m0 + row) * K + k0) * 2 + scb;
      gl_lds16(ga, (char*)As + c * 1024);
      const char* gw = (const char*)W + ((size_t)(n0 + row) * K + k0) * 2 + scb;
      gl_lds16(gw, (char*)Bs + c * 1024);
    }
    __syncthreads();
    s16x8 af[4], bfr[4];
#pragma unroll
    for (int mi = 0; mi < 4; ++mi) {
      int row = wm + mi * 16 + lrow;
      af[mi] = *reinterpret_cast<const s16x8*>((const char*)As + row * 64 + lkk * 16);
    }
#pragma unroll
    for (int ni = 0; ni < 4; ++ni) {
      int row = wn + ni * 16 + lrow;
      bfr[ni] = *reinterpret_cast<const s16x8*>((const char*)Bs + row * 64 + lkk * 16);
    }
#pragma unroll
    for (int mi = 0; mi < 4; ++mi)
#pragma unroll
      for (int ni = 0; ni < 4; ++ni)
        acc[mi][ni] = __builtin_amdgcn_mfma_f32_16x16x32_bf16(af[mi], bfr[ni], acc[mi][ni], 0, 0, 0);
  }

  if (mode == 2) {
#pragma unroll
    for (int mi = 0; mi < 4; ++mi)
#pragma unroll
      for (int ni = 0; ni < 4; ++ni) {
        int col = n0 + wn + ni * 16 + lrow;
        int mrow = m0 + wm + mi * 16 + lkk * 4;
        ushort4 o;
        o.x = f2bf(acc[mi][ni][0]); o.y = f2bf(acc[mi][ni][1]);
        o.z = f2bf(acc[mi][ni][2]); o.w = f2bf(acc[mi][ni][3]);
        *reinterpret_cast<ushort4*>(Cvt + (size_t)col * M + mrow) = o;
      }
  } else {
    // RoPE epilogue: pair (even,odd) cols live in adjacent lanes (lrow^1).
    unsigned short* C = (mode == 0) ? Cq : Ck;
    int N = (mode == 0) ? D_MODEL : KVD;
    float qs = (mode == 0) ? QSC : 1.0f;
#pragma unroll
    for (int mi = 0; mi < 4; ++mi)
#pragma unroll
      for (int ni = 0; ni < 4; ++ni) {
        int col = n0 + wn + ni * 16 + lrow;
        int pair = (col & 63) >> 1;
        float sgn = (col & 1) ? 1.0f : -1.0f;
#pragma unroll
        for (int r = 0; r < 4; ++r) {
          int row = m0 + wm + mi * 16 + lkk * 4 + r;
          int s = row & (S_LEN - 1);
          float cv = cosb[s * 32 + pair];
          float sv = sinb[s * 32 + pair];
          float v = acc[mi][ni][r];
          float p = __shfl_xor(v, 1, 64);
          C[(size_t)row * N + col] = f2bf((v * cv + sgn * p * sv) * qs);
        }
      }
  }
}

// ---------------- output projection: m97 structure, f32 out ----------------
__global__ __launch_bounds__(256) void gemm_out(const unsigned short* __restrict__ A,
                                                const unsigned short* __restrict__ W,
                                                float* __restrict__ Cf,
                                                int M, int N, int K) {
  __shared__ alignas(16) short As[128 * 32];
  __shared__ alignas(16) short Bs[128 * 32];
  int tid = threadIdx.x;
  int lane = tid & 63, wid = tid >> 6;
  int m0 = blockIdx.y * 128;
  int n0 = blockIdx.x * 128;
  int wm = (wid >> 1) * 64, wn = (wid & 1) * 64;
  int lrow = lane & 15, lkk = lane >> 4;
  int srow = lane >> 2;
  int scb  = (lane & 3) * 16;
  f32x4 acc[4][4] = {};

  for (int k0 = 0; k0 < K; k0 += 32) {
    __syncthreads();
#pragma unroll
    for (int i = 0; i < 2; ++i) {
      int c = wid * 2 + i;
      int row = c * 16 + srow;
      const char* ga = (const char*)A + ((size_t)(m0 + row) * K + k0) * 2 + scb;
      gl_lds16(ga, (char*)As + c * 1024);
      const char* gw = (const char*)W + ((size_t)(n0 + row) * K + k0) * 2 + scb;
      gl_lds16(gw, (char*)Bs + c * 1024);
    }
    __syncthreads();
    s16x8 af[4], bfr[4];
#pragma unroll
    for (int mi = 0; mi < 4; ++mi) {
      int row = wm + mi * 16 + lrow;
      af[mi] = *reinterpret_cast<const s16x8*>((const char*)As + row * 64 + lkk * 16);
    }
#pragma unroll
    for (int ni = 0; ni < 4; ++ni) {
      int row = wn + ni * 16 + lrow;
      bfr[ni] = *reinterpret_cast<const s16x8*>((const char*)Bs + row * 64 + lkk * 16);
    }
#pragma unroll
    for (int mi = 0; mi < 4; ++mi)
#pragma unroll
      for (int ni = 0; ni < 4; ++ni)
        acc[mi][ni] = __builtin_amdgcn_mfma_f32_16x16x32_bf16(af[mi], bfr[ni], acc[mi][ni], 0, 0, 0);
  }

#pragma unroll
  for (int mi = 0; mi < 4; ++mi)
#pragma unroll
    for (int ni = 0; ni < 4; ++ni)
#pragma unroll
      for (int r = 0; r < 4; ++r) {
        int row = m0 + wm + mi * 16 + lkk * 4 + r;
        int col = n0 + wn + ni * 16 + lrow;
        Cf[(size_t)row * N + col] = acc[mi][ni][r];
      }
}

// ---------------- Flash attention (causal, GQA rep=4), swapped QK^T ----------------
// 4 waves x 32 q rows (two 16-row fragment groups per wave) -> K/V frag reads shared
// by both groups: LDS traffic halved vs 1 group. QBLK=128, balanced pairing x & 15-x.
// grid (8, B*NH) = 512 blocks, 256 threads. Dbuf LDS, 1 barrier/tile, defer-max,
// exp2-domain softmax (Q pre-scaled by QSC in gemm_qkv epilogue).
__global__ __launch_bounds__(256) void attn_kernel(const unsigned short* __restrict__ Q,
                                                   const unsigned short* __restrict__ Kb,
                                                   const unsigned short* __restrict__ Vt,
                                                   unsigned short* __restrict__ O) {
  __shared__ alignas(16) short Ks[2][64 * 64];   // [kv][d], 128B rows, XOR (row&7)<<4
  __shared__ alignas(16) short Vs[2][64 * 64];   // [d][kv] (from global Vt), same swizzle

  int tid = threadIdx.x, lane = tid & 63, wid = tid >> 6;   // wid 0..3
  int qi = lane & 15, lk = lane >> 4;
  int bh = blockIdx.y;
  int b = bh / NH, h = bh % NH, kvh = h >> 2;
  size_t bS = (size_t)b * S_LEN;
  int srow = tid >> 3;           // 0..31 (two passes: +0, +32)
  int scb  = (tid & 7) * 16;     // byte col within 128B row
  int sw0  = (srow & 7) << 4;

  const char* kbG = (const char*)Kb + (bS * KVD + (size_t)kvh * HD_) * 2;
  const char* vtG = (const char*)Vt + ((size_t)(kvh * 64) * MTOT + bS) * 2;

  s16x8 kr0, kr1, vr0, vr1;
  auto GLOAD = [&](int kv0) {
    kr0 = *reinterpret_cast<const s16x8*>(kbG + (size_t)(kv0 + srow) * (KVD * 2) + scb);
    kr1 = *reinterpret_cast<const s16x8*>(kbG + (size_t)(kv0 + srow + 32) * (KVD * 2) + scb);
    vr0 = *reinterpret_cast<const s16x8*>(vtG + (size_t)srow * (MTOT * 2) + kv0 * 2 + scb);
    vr1 = *reinterpret_cast<const s16x8*>(vtG + (size_t)(srow + 32) * (MTOT * 2) + kv0 * 2 + scb);
  };
  auto SWRITE = [&](int bf) {
    *reinterpret_cast<s16x8*>((char*)Ks[bf] + srow * 128 + (scb ^ sw0)) = kr0;
    *reinterpret_cast<s16x8*>((char*)Ks[bf] + (srow + 32) * 128 + (scb ^ sw0)) = kr1;
    *reinterpret_cast<s16x8*>((char*)Vs[bf] + srow * 128 + (scb ^ sw0)) = vr0;
    *reinterpret_cast<s16x8*>((char*)Vs[bf] + (srow + 32) * 128 + (scb ^ sw0)) = vr1;
  };

#pragma unroll 1
  for (int job = 0; job < 2; ++job) {
    int qtile = (job == 0) ? (int)blockIdx.x : 15 - (int)blockIdx.x;
    int q0 = qtile * 128;
    int nt = 2 * qtile + 2;
    int qw = q0 + wid * 32;            // wave's first q row (32 rows, 2 groups of 16)

    // Q B-frags per group g: col=qi, k=d contiguous
    const unsigned short* qp0 = Q + (bS + qw + qi) * D_MODEL + h * HD_;
    const unsigned short* qp1 = Q + (bS + qw + 16 + qi) * D_MODEL + h * HD_;
    s16x8 qfa[2], qfb[2];
    qfa[0] = *reinterpret_cast<const s16x8*>(qp0 + lk * 8);
    qfb[0] = *reinterpret_cast<const s16x8*>(qp0 + 32 + lk * 8);
    qfa[1] = *reinterpret_cast<const s16x8*>(qp1 + lk * 8);
    qfb[1] = *reinterpret_cast<const s16x8*>(qp1 + 32 + lk * 8);

    f32x4 o_acc[2][4] = {};
    float m_run[2] = {-3.0e38f, -3.0e38f};
    float l_run[2] = {0.f, 0.f};

    GLOAD(0);
    SWRITE(0);
    __syncthreads();
    int cur = 0;

    for (int t = 0; t < nt; ++t) {
      if (t + 1 < nt) GLOAD((t + 1) * 64);   // issue early; latency hides under compute

      if (64 * t <= qw + 31) {   // wave-uniform: any unmasked element in this tile?
        const char* kbase = (const char*)Ks[cur];
        const char* vbase = (const char*)Vs[cur];

        // K A-frags (shared by both q groups)
        s16x8 ka0[4], ka1[4];
#pragma unroll
        for (int mt = 0; mt < 4; ++mt) {
          int row = mt * 16 + qi;
          int sw = (row & 7) << 4;
          ka0[mt] = *reinterpret_cast<const s16x8*>(kbase + row * 128 + ((lk * 16) ^ sw));
          ka1[mt] = *reinterpret_cast<const s16x8*>(kbase + row * 128 + ((64 + lk * 16) ^ sw));
        }

        // S^T tiles: st[g][mt][r] = S^T[kv=64t+mt*16+4lk+r][q = qw+16g+qi]
        f32x4 st[2][4];
        __builtin_amdgcn_s_setprio(1);
#pragma unroll
        for (int g = 0; g < 2; ++g)
#pragma unroll
          for (int mt = 0; mt < 4; ++mt) {
            f32x4 a = {};
            a = __builtin_amdgcn_mfma_f32_16x16x32_bf16(ka0[mt], qfa[g], a, 0, 0, 0);
            a = __builtin_amdgcn_mfma_f32_16x16x32_bf16(ka1[mt], qfb[g], a, 0, 0, 0);
            st[g][mt] = a;
          }
        __builtin_amdgcn_s_setprio(0);

        // V B-frags (shared by both groups) — issue before softmax to overlap DS latency
        s16x8 vb0[4], vb1[4];
#pragma unroll
        for (int n = 0; n < 4; ++n) {
          int vrw = n * 16 + qi;
          int sw = (vrw & 7) << 4;
          vb0[n] = *reinterpret_cast<const s16x8*>(vbase + vrw * 128 + ((lk * 16) ^ sw));
          vb1[n] = *reinterpret_cast<const s16x8*>(vbase + vrw * 128 + ((64 + lk * 16) ^ sw));
        }

        if (t >= nt - 2) {  // diagonal tiles: mask kv > q (global indices)
#pragma unroll
          for (int g = 0; g < 2; ++g) {
            int ql = qw + 16 * g + qi;
#pragma unroll
            for (int mt = 0; mt < 4; ++mt)
#pragma unroll
              for (int r = 0; r < 4; ++r) {
                int kvg = 64 * t + mt * 16 + 4 * lk + r;
                if (kvg > ql) st[g][mt][r] = -3.0e38f;
              }
          }
        }

        u32 pk[2][4][2];
#pragma unroll
        for (int g = 0; g < 2; ++g) {
          // online softmax (exp2 domain); row q lives in lanes {qi, qi+16, qi+32, qi+48}
          float pmax = st[g][0][0];
#pragma unroll
          for (int mt = 0; mt < 4; ++mt)
#pragma unroll
            for (int r = 0; r < 4; ++r) pmax = fmaxf(pmax, st[g][mt][r]);
          pmax = fmaxf(pmax, __shfl_xor(pmax, 16, 64));
          pmax = fmaxf(pmax, __shfl_xor(pmax, 32, 64));

          // T13 defer-max: skip rescale while growth <= 8 (P bounded by 2^8)
          if (!__all(pmax <= m_run[g] + 8.0f)) {
            float mnew = fmaxf(m_run[g], pmax);
            float alpha = fexp2(m_run[g] - mnew);
            m_run[g] = mnew;
            l_run[g] *= alpha;
            float ar[4];
#pragma unroll
            for (int r = 0; r < 4; ++r) ar[r] = __shfl(alpha, 4 * lk + r, 64);
#pragma unroll
            for (int n = 0; n < 4; ++n)
#pragma unroll
              for (int r = 0; r < 4; ++r) o_acc[g][n][r] *= ar[r];
          }

          float psum = 0.f;
#pragma unroll
          for (int mt = 0; mt < 4; ++mt)
#pragma unroll
            for (int r = 0; r < 4; ++r) {
              float p = fexp2(st[g][mt][r] - m_run[g]);
              st[g][mt][r] = p;
              psum += p;
            }
          psum += __shfl_xor(psum, 16, 64);
          psum += __shfl_xor(psum, 32, 64);
          l_run[g] += psum;

          // pack P^T pairs to bf16 (RNE)
#pragma unroll
          for (int mt = 0; mt < 4; ++mt)
#pragma unroll
            for (int w = 0; w < 2; ++w)
              pk[g][mt][w] = (u32)f2bf(st[g][mt][2 * w]) | ((u32)f2bf(st[g][mt][2 * w + 1]) << 16);
        }

        // redistribute P^T -> PV A-frags + PV MFMA, per group
        int s0 = qi + 32 * (lk & 1);
        int s2 = s0 + 16;
        bool hiw = lk >= 2;
#pragma unroll
        for (int g = 0; g < 2; ++g) {
          s16x8 pa[2];
#pragma unroll
          for (int ks = 0; ks < 2; ++ks) {
            u32 a0 = (u32)__shfl((int)pk[g][2 * ks][0], s0, 64), b0 = (u32)__shfl((int)pk[g][2 * ks + 1][0], s0, 64);
            u32 a1 = (u32)__shfl((int)pk[g][2 * ks][1], s0, 64), b1 = (u32)__shfl((int)pk[g][2 * ks + 1][1], s0, 64);
            u32 a2 = (u32)__shfl((int)pk[g][2 * ks][0], s2, 64), b2 = (u32)__shfl((int)pk[g][2 * ks + 1][0], s2, 64);
            u32 a3 = (u32)__shfl((int)pk[g][2 * ks][1], s2, 64), b3 = (u32)__shfl((int)pk[g][2 * ks + 1][1], s2, 64);
            u32x4 wv_;
            wv_[0] = hiw ? b0 : a0; wv_[1] = hiw ? b1 : a1;
            wv_[2] = hiw ? b2 : a2; wv_[3] = hiw ? b3 : a3;
            pa[ks] = __builtin_bit_cast(s16x8, wv_);
          }
          __builtin_amdgcn_s_setprio(1);
#pragma unroll
          for (int n = 0; n < 4; ++n) {
            o_acc[g][n] = __builtin_amdgcn_mfma_f32_16x16x32_bf16(pa[0], vb0[n], o_acc[g][n], 0, 0, 0);
            o_acc[g][n] = __builtin_amdgcn_mfma_f32_16x16x32_bf16(pa[1], vb1[n], o_acc[g][n], 0, 0, 0);
          }
          __builtin_amdgcn_s_setprio(0);
        }
      }

      if (t + 1 < nt) SWRITE(cur ^ 1);   // next tile into other buffer
      __syncthreads();
      cur ^= 1;
    }

    // epilogue: per group, O C-layout row q=4lk+r, col d=16n+qi
#pragma unroll
    for (int g = 0; g < 2; ++g) {
      float linv[4];
#pragma unroll
      for (int r = 0; r < 4; ++r) linv[r] = 1.0f / __shfl(l_run[g], 4 * lk + r, 64);
#pragma unroll
      for (int n = 0; n < 4; ++n)
#pragma unroll
        for (int r = 0; r < 4; ++r) {
          size_t row = bS + qw + 16 * g + 4 * lk + r;
          int col = h * HD_ + n * 16 + qi;
          O[row * D_MODEL + col] = f2bf(o_acc[g][n][r] * linv[r]);
        }
    }
  }
}

// ---------------- launch ----------------
extern "C" void kernel_launch(void* const* d_in, const int* in_sizes, int n_in,
                              void* d_out, int out_size, void* d_ws, size_t ws_size,
                              hipStream_t stream) {
  const float* x  = (const float*)d_in[0];
  const float* fc = (const float*)d_in[1];
  const float* fs = (const float*)d_in[2];
  const float* wq = (const float*)d_in[3];
  const float* wk = (const float*)d_in[4];
  const float* wv = (const float*)d_in[5];
  const float* wo = (const float*)d_in[6];
  float* out = (float*)d_out;

  const size_t nx  = (size_t)BATCH * S_LEN * D_MODEL;
  const size_t nw  = (size_t)D_MODEL * D_MODEL;
  const size_t nwk = (size_t)KVD * D_MODEL;
  const size_t nkv = (size_t)BATCH * S_LEN * KVD;

  char* ws = (char*)d_ws;
  unsigned short* xb  = (unsigned short*)ws;  ws += nx  * 2;
  unsigned short* wqb = (unsigned short*)ws;  ws += nw  * 2;
  unsigned short* wkb = (unsigned short*)ws;  ws += nwk * 2;
  unsigned short* wvb = (unsigned short*)ws;  ws += nwk * 2;
  unsigned short* wob = (unsigned short*)ws;  ws += nw  * 2;
  unsigned short* qb  = (unsigned short*)ws;  ws += nx  * 2;
  unsigned short* kb  = (unsigned short*)ws;  ws += nkv * 2;
  unsigned short* vtb = (unsigned short*)ws;  ws += nkv * 2;   // V^T [KVD][MTOT]
  unsigned short* ab  = (unsigned short*)ws;  ws += nx  * 2;

  {
    int nx4 = nx / 4, na4 = nw / 4, nb4 = nwk / 4, nc4 = nwk / 4, nd4 = nw / 4;
    int tot = nx4 + na4 + nb4 + nc4 + nd4;
    cvt5_kernel<<<dim3((tot + 255) / 256), dim3(256), 0, stream>>>(x, wq, wk, wv, wo,
                                                                   xb, wqb, wkb, wvb, wob,
                                                                   nx4, na4, nb4, nc4, nd4);
  }

  const int M = BATCH * S_LEN;  // 4096
  gemm_qkv<<<dim3(24, M / 128), dim3(256), 0, stream>>>(xb, wqb, wkb, wvb, fc, fs, qb, kb, vtb, M, D_MODEL);

  attn_kernel<<<dim3(8, BATCH * NH), dim3(256), 0, stream>>>(qb, kb, vtb, ab);

  gemm_out<<<dim3(D_MODEL / 128, M / 128), dim3(256), 0, stream>>>(ab, wob, out, M, D_MODEL, D_MODEL);
}

// Round 12
// 350.061 us; speedup vs baseline: 1.1669x; 1.1669x over previous
//
#include <hip/hip_runtime.h>
#include <cstdint>
#include <cstddef>

#define S_LEN 2048
#define D_MODEL 2048
#define NH 32
#define NKV 8
#define HD_ 64
#define BATCH 2
#define KVD 512
#define MTOT 4096
#define QSC 0.18033688011112042f   // 0.125 * log2(e): QK^T lands in exp2 domain

typedef float f32x4 __attribute__((ext_vector_type(4)));
typedef short s16x8 __attribute__((ext_vector_type(8)));
typedef unsigned int u32;
typedef unsigned int u32x4 __attribute__((ext_vector_type(4)));

__device__ __forceinline__ unsigned short f2bf(float f) {
  unsigned int u = __builtin_bit_cast(unsigned int, f);
  u = (u + 0x7fffu + ((u >> 16) & 1u)) >> 16;
  return (unsigned short)u;
}
__device__ __forceinline__ float bf2f(unsigned short h) {
  return __builtin_bit_cast(float, ((unsigned int)h) << 16);
}
__device__ __forceinline__ float fexp2(float x) {
#if __has_builtin(__builtin_amdgcn_exp2f)
  return __builtin_amdgcn_exp2f(x);
#else
  return exp2f(x);
#endif
}

// async global->LDS, 16B per lane; LDS dest = wave-uniform base + lane*16 (linear only)
__device__ __forceinline__ void gl_lds16(const void* g, void* l) {
  __builtin_amdgcn_global_load_lds((const __attribute__((address_space(1))) u32*)g,
                                   (__attribute__((address_space(3))) u32*)l, 16, 0, 0);
}

// ---------------- fused 5-tensor f32 -> bf16 convert ----------------
__global__ void cvt5_kernel(const float* __restrict__ x, const float* __restrict__ a,
                            const float* __restrict__ b, const float* __restrict__ c,
                            const float* __restrict__ d,
                            unsigned short* __restrict__ ox, unsigned short* __restrict__ oa,
                            unsigned short* __restrict__ ob, unsigned short* __restrict__ oc,
                            unsigned short* __restrict__ od,
                            int nx4, int na4, int nb4, int nc4, int nd4) {
  int j = blockIdx.x * blockDim.x + threadIdx.x;
  const float* src; unsigned short* dst;
  if (j < nx4) { src = x; dst = ox; }
  else {
    j -= nx4;
    if (j < na4) { src = a; dst = oa; }
    else {
      j -= na4;
      if (j < nb4) { src = b; dst = ob; }
      else {
        j -= nb4;
        if (j < nc4) { src = c; dst = oc; }
        else {
          j -= nc4;
          if (j >= nd4) return;
          src = d; dst = od;
        }
      }
    }
  }
  float4 v = reinterpret_cast<const float4*>(src)[j];
  ushort4 o;
  o.x = f2bf(v.x); o.y = f2bf(v.y); o.z = f2bf(v.z); o.w = f2bf(v.w);
  reinterpret_cast<ushort4*>(dst)[j] = o;
}

// ---------------- fused QKV projection with RoPE epilogue ----------------
// m97 structure. 1-D grid 768, XCD-clustered decode: xcd=bid&7 owns m-rows xcd*4..+3,
// all 24 n-blocks -> x-panel (512KB) fetched once per XCD (L2-resident, 2MB/XCD).
// nb: 0..15 -> Q (RoPE + QSC), 16..19 -> K (RoPE), 20..23 -> V (transposed out).
__global__ __launch_bounds__(256) void gemm_qkv(const unsigned short* __restrict__ A,
                                                const unsigned short* __restrict__ Wq,
                                                const unsigned short* __restrict__ Wk,
                                                const unsigned short* __restrict__ Wv,
                                                const float* __restrict__ cosb,
                                                const float* __restrict__ sinb,
                                                unsigned short* __restrict__ Cq,
                                                unsigned short* __restrict__ Ck,
                                                unsigned short* __restrict__ Cvt,
                                                int M, int K) {
  __shared__ alignas(16) short As[128 * 32];
  __shared__ alignas(16) short Bs[128 * 32];
  int tid = threadIdx.x;
  int lane = tid & 63, wid = tid >> 6;
  int bid = blockIdx.x;                 // 0..767
  int xcd = bid & 7, ii = bid >> 3;     // 96 blocks per XCD
  int mrow = xcd * 4 + ii / 24;         // 0..31
  int nb = ii % 24;                     // 0..23
  const unsigned short* W; int n0, mode;
  if (nb < 16)      { W = Wq; n0 = nb * 128;        mode = 0; }
  else if (nb < 20) { W = Wk; n0 = (nb - 16) * 128; mode = 1; }
  else              { W = Wv; n0 = (nb - 20) * 128; mode = 2; }
  int m0 = mrow * 128;
  int wm = (wid >> 1) * 64, wn = (wid & 1) * 64;
  int lrow = lane & 15, lkk = lane >> 4;
  int srow = lane >> 2;
  int scb  = (lane & 3) * 16;
  f32x4 acc[4][4] = {};

  for (int k0 = 0; k0 < K; k0 += 32) {
    __syncthreads();
#pragma unroll
    for (int i = 0; i < 2; ++i) {
      int c = wid * 2 + i;
      int row = c * 16 + srow;
      const char* ga = (const char*)A + ((size_t)(m0 + row) * K + k0) * 2 + scb;
      gl_lds16(ga, (char*)As + c * 1024);
      const char* gw = (const char*)W + ((size_t)(n0 + row) * K + k0) * 2 + scb;
      gl_lds16(gw, (char*)Bs + c * 1024);
    }
    __syncthreads();
    s16x8 af[4], bfr[4];
#pragma unroll
    for (int mi = 0; mi < 4; ++mi) {
      int row = wm + mi * 16 + lrow;
      af[mi] = *reinterpret_cast<const s16x8*>((const char*)As + row * 64 + lkk * 16);
    }
#pragma unroll
    for (int ni = 0; ni < 4; ++ni) {
      int row = wn + ni * 16 + lrow;
      bfr[ni] = *reinterpret_cast<const s16x8*>((const char*)Bs + row * 64 + lkk * 16);
    }
#pragma unroll
    for (int mi = 0; mi < 4; ++mi)
#pragma unroll
      for (int ni = 0; ni < 4; ++ni)
        acc[mi][ni] = __builtin_amdgcn_mfma_f32_16x16x32_bf16(af[mi], bfr[ni], acc[mi][ni], 0, 0, 0);
  }

  if (mode == 2) {
#pragma unroll
    for (int mi = 0; mi < 4; ++mi)
#pragma unroll
      for (int ni = 0; ni < 4; ++ni) {
        int col = n0 + wn + ni * 16 + lrow;
        int mr = m0 + wm + mi * 16 + lkk * 4;
        ushort4 o;
        o.x = f2bf(acc[mi][ni][0]); o.y = f2bf(acc[mi][ni][1]);
        o.z = f2bf(acc[mi][ni][2]); o.w = f2bf(acc[mi][ni][3]);
        *reinterpret_cast<ushort4*>(Cvt + (size_t)col * M + mr) = o;
      }
  } else {
    // RoPE epilogue: pair (even,odd) cols live in adjacent lanes (lrow^1).
    unsigned short* C = (mode == 0) ? Cq : Ck;
    int N = (mode == 0) ? D_MODEL : KVD;
    float qs = (mode == 0) ? QSC : 1.0f;
#pragma unroll
    for (int mi = 0; mi < 4; ++mi)
#pragma unroll
      for (int ni = 0; ni < 4; ++ni) {
        int col = n0 + wn + ni * 16 + lrow;
        int pair = (col & 63) >> 1;
        float sgn = (col & 1) ? 1.0f : -1.0f;
#pragma unroll
        for (int r = 0; r < 4; ++r) {
          int row = m0 + wm + mi * 16 + lkk * 4 + r;
          int s = row & (S_LEN - 1);
          float cv = cosb[s * 32 + pair];
          float sv = sinb[s * 32 + pair];
          float v = acc[mi][ni][r];
          float p = __shfl_xor(v, 1, 64);
          C[(size_t)row * N + col] = f2bf((v * cv + sgn * p * sv) * qs);
        }
      }
  }
}

// ---------------- output projection: m97 structure, f32 out, XCD-clustered grid ----------------
__global__ __launch_bounds__(256) void gemm_out(const unsigned short* __restrict__ A,
                                                const unsigned short* __restrict__ W,
                                                float* __restrict__ Cf,
                                                int M, int N, int K) {
  __shared__ alignas(16) short As[128 * 32];
  __shared__ alignas(16) short Bs[128 * 32];
  int tid = threadIdx.x;
  int lane = tid & 63, wid = tid >> 6;
  int bid = blockIdx.x;                 // 0..511
  int xcd = bid & 7, ii = bid >> 3;     // 64 per XCD
  int m0 = (xcd * 4 + ii / 16) * 128;
  int n0 = (ii % 16) * 128;
  int wm = (wid >> 1) * 64, wn = (wid & 1) * 64;
  int lrow = lane & 15, lkk = lane >> 4;
  int srow = lane >> 2;
  int scb  = (lane & 3) * 16;
  f32x4 acc[4][4] = {};

  for (int k0 = 0; k0 < K; k0 += 32) {
    __syncthreads();
#pragma unroll
    for (int i = 0; i < 2; ++i) {
      int c = wid * 2 + i;
      int row = c * 16 + srow;
      const char* ga = (const char*)A + ((size_t)(m0 + row) * K + k0) * 2 + scb;
      gl_lds16(ga, (char*)As + c * 1024);
      const char* gw = (const char*)W + ((size_t)(n0 + row) * K + k0) * 2 + scb;
      gl_lds16(gw, (char*)Bs + c * 1024);
    }
    __syncthreads();
    s16x8 af[4], bfr[4];
#pragma unroll
    for (int mi = 0; mi < 4; ++mi) {
      int row = wm + mi * 16 + lrow;
      af[mi] = *reinterpret_cast<const s16x8*>((const char*)As + row * 64 + lkk * 16);
    }
#pragma unroll
    for (int ni = 0; ni < 4; ++ni) {
      int row = wn + ni * 16 + lrow;
      bfr[ni] = *reinterpret_cast<const s16x8*>((const char*)Bs + row * 64 + lkk * 16);
    }
#pragma unroll
    for (int mi = 0; mi < 4; ++mi)
#pragma unroll
      for (int ni = 0; ni < 4; ++ni)
        acc[mi][ni] = __builtin_amdgcn_mfma_f32_16x16x32_bf16(af[mi], bfr[ni], acc[mi][ni], 0, 0, 0);
  }

#pragma unroll
  for (int mi = 0; mi < 4; ++mi)
#pragma unroll
    for (int ni = 0; ni < 4; ++ni)
#pragma unroll
      for (int r = 0; r < 4; ++r) {
        int row = m0 + wm + mi * 16 + lkk * 4 + r;
        int col = n0 + wn + ni * 16 + lrow;
        Cf[(size_t)row * N + col] = acc[mi][ni][r];
      }
}

// ---------------- Flash attention (round-6 proven structure: 87.5 us) ----------------
// 8 waves x 16 q rows, QBLK=128. Balanced pairing x & 15-x -> 34 KV-tiles/block.
// grid (8, B*NH) = 512 blocks, 512 threads, VGPR 52, occ 38%. Dbuf LDS, 1 barrier/tile.
// exp2-domain softmax (Q pre-scaled by QSC in gemm_qkv). T13 defer-max. Wave-uniform guard.
__global__ __launch_bounds__(512) void attn_kernel(const unsigned short* __restrict__ Q,
                                                   const unsigned short* __restrict__ Kb,
                                                   const unsigned short* __restrict__ Vt,
                                                   unsigned short* __restrict__ O) {
  __shared__ alignas(16) short Ks[2][64 * 64];   // [kv][d], 128B rows, XOR (row&7)<<4
  __shared__ alignas(16) short Vs[2][64 * 64];   // [d][kv] (from global Vt), same swizzle

  int tid = threadIdx.x, lane = tid & 63, wid = tid >> 6;   // wid 0..7
  int qi = lane & 15, lk = lane >> 4;
  int bh = blockIdx.y;
  int b = bh / NH, h = bh % NH, kvh = h >> 2;
  size_t bS = (size_t)b * S_LEN;
  int srow = tid >> 3;           // 0..63: one 16B chunk per thread
  int scb  = (tid & 7) * 16;     // byte col within 128B row
  int sw0  = (srow & 7) << 4;

  const char* kbG = (const char*)Kb + (bS * KVD + (size_t)kvh * HD_) * 2;
  const char* vtG = (const char*)Vt + ((size_t)(kvh * 64) * MTOT + bS) * 2;

  s16x8 kr, vr;
  auto GLOAD = [&](int kv0) {
    kr = *reinterpret_cast<const s16x8*>(kbG + (size_t)(kv0 + srow) * (KVD * 2) + scb);
    vr = *reinterpret_cast<const s16x8*>(vtG + (size_t)srow * (MTOT * 2) + kv0 * 2 + scb);
  };
  auto SWRITE = [&](int bf) {
    *reinterpret_cast<s16x8*>((char*)Ks[bf] + srow * 128 + (scb ^ sw0)) = kr;
    *reinterpret_cast<s16x8*>((char*)Vs[bf] + srow * 128 + (scb ^ sw0)) = vr;
  };

#pragma unroll 1
  for (int job = 0; job < 2; ++job) {
    int qtile = (job == 0) ? (int)blockIdx.x : 15 - (int)blockIdx.x;
    int q0 = qtile * 128;
    int nt = 2 * qtile + 2;
    int qlmax = q0 + wid * 16 + 15;   // wave's max q row

    const unsigned short* qptr = Q + (bS + q0 + wid * 16 + qi) * D_MODEL + h * HD_;
    s16x8 qf0 = *reinterpret_cast<const s16x8*>(qptr + lk * 8);
    s16x8 qf1 = *reinterpret_cast<const s16x8*>(qptr + 32 + lk * 8);

    f32x4 o_acc[4] = {};
    float m_run = -3.0e38f, l_run = 0.f;

    GLOAD(0);
    SWRITE(0);
    __syncthreads();
    int cur = 0;

    for (int t = 0; t < nt; ++t) {
      if (t + 1 < nt) GLOAD((t + 1) * 64);   // issue early; latency hides under compute

      if (64 * t <= qlmax) {   // wave-uniform: any unmasked element in this tile?
        const char* kbase = (const char*)Ks[cur];
        const char* vbase = (const char*)Vs[cur];

        // S^T tiles: st[mt][r] = S^T[kv = 64t + mt*16 + 4*lk + r][q = q0 + wid*16 + qi]
        f32x4 st[4];
        __builtin_amdgcn_s_setprio(1);
#pragma unroll
        for (int mt = 0; mt < 4; ++mt) {
          int row = mt * 16 + qi;
          int sw = (row & 7) << 4;
          s16x8 ka0 = *reinterpret_cast<const s16x8*>(kbase + row * 128 + ((lk * 16) ^ sw));
          s16x8 ka1 = *reinterpret_cast<const s16x8*>(kbase + row * 128 + ((64 + lk * 16) ^ sw));
          f32x4 a = {};
          a = __builtin_amdgcn_mfma_f32_16x16x32_bf16(ka0, qf0, a, 0, 0, 0);
          a = __builtin_amdgcn_mfma_f32_16x16x32_bf16(ka1, qf1, a, 0, 0, 0);
          st[mt] = a;
        }
        __builtin_amdgcn_s_setprio(0);

        if (t >= nt - 2) {  // diagonal tiles: mask kv > q (global indices)
          int ql = q0 + wid * 16 + qi;
#pragma unroll
          for (int mt = 0; mt < 4; ++mt)
#pragma unroll
            for (int r = 0; r < 4; ++r) {
              int kvg = 64 * t + mt * 16 + 4 * lk + r;
              if (kvg > ql) st[mt][r] = -3.0e38f;
            }
        }

        // online softmax (exp2 domain); row q=qi lives in lanes {qi, qi+16, qi+32, qi+48}
        float pmax = st[0][0];
#pragma unroll
        for (int mt = 0; mt < 4; ++mt)
#pragma unroll
          for (int r = 0; r < 4; ++r) pmax = fmaxf(pmax, st[mt][r]);
        pmax = fmaxf(pmax, __shfl_xor(pmax, 16, 64));
        pmax = fmaxf(pmax, __shfl_xor(pmax, 32, 64));

        // T13 defer-max: skip rescale while growth <= 8 (P bounded by 2^8)
        if (!__all(pmax <= m_run + 8.0f)) {
          float mnew = fmaxf(m_run, pmax);
          float alpha = fexp2(m_run - mnew);
          m_run = mnew;
          l_run *= alpha;
          float ar[4];
#pragma unroll
          for (int r = 0; r < 4; ++r) ar[r] = __shfl(alpha, 4 * lk + r, 64);
#pragma unroll
          for (int n = 0; n < 4; ++n)
#pragma unroll
            for (int r = 0; r < 4; ++r) o_acc[n][r] *= ar[r];
        }

        float psum = 0.f;
#pragma unroll
        for (int mt = 0; mt < 4; ++mt)
#pragma unroll
          for (int r = 0; r < 4; ++r) {
            float p = fexp2(st[mt][r] - m_run);
            st[mt][r] = p;
            psum += p;
          }
        psum += __shfl_xor(psum, 16, 64);
        psum += __shfl_xor(psum, 32, 64);
        l_run += psum;

        // pack P^T pairs to bf16 (RNE)
        u32 pk[4][2];
#pragma unroll
        for (int mt = 0; mt < 4; ++mt)
#pragma unroll
          for (int w = 0; w < 2; ++w)
            pk[mt][w] = (u32)f2bf(st[mt][2 * w]) | ((u32)f2bf(st[mt][2 * w + 1]) << 16);

        // redistribute P^T -> PV A-frags: pa[ks] word u = P[q=qi][kv=32ks+8lk+2u{,+1}]
        int s0 = qi + 32 * (lk & 1);
        int s2 = s0 + 16;
        bool hiw = lk >= 2;
        s16x8 pa[2];
#pragma unroll
        for (int ks = 0; ks < 2; ++ks) {
          u32 a0 = (u32)__shfl((int)pk[2 * ks][0], s0, 64), b0 = (u32)__shfl((int)pk[2 * ks + 1][0], s0, 64);
          u32 a1 = (u32)__shfl((int)pk[2 * ks][1], s0, 64), b1 = (u32)__shfl((int)pk[2 * ks + 1][1], s0, 64);
          u32 a2 = (u32)__shfl((int)pk[2 * ks][0], s2, 64), b2 = (u32)__shfl((int)pk[2 * ks + 1][0], s2, 64);
          u32 a3 = (u32)__shfl((int)pk[2 * ks][1], s2, 64), b3 = (u32)__shfl((int)pk[2 * ks + 1][1], s2, 64);
          u32x4 wv_;
          wv_[0] = hiw ? b0 : a0; wv_[1] = hiw ? b1 : a1;
          wv_[2] = hiw ? b2 : a2; wv_[3] = hiw ? b3 : a3;
          pa[ks] = __builtin_bit_cast(s16x8, wv_);
        }

        // PV: O[q][d] += P * V ; B-frag from Vs rows (d), contiguous kv
        __builtin_amdgcn_s_setprio(1);
#pragma unroll
        for (int n = 0; n < 4; ++n) {
          int vrw = n * 16 + qi;
          int sw = (vrw & 7) << 4;
          s16x8 vb0 = *reinterpret_cast<const s16x8*>(vbase + vrw * 128 + ((lk * 16) ^ sw));
          s16x8 vb1 = *reinterpret_cast<const s16x8*>(vbase + vrw * 128 + ((64 + lk * 16) ^ sw));
          o_acc[n] = __builtin_amdgcn_mfma_f32_16x16x32_bf16(pa[0], vb0, o_acc[n], 0, 0, 0);
          o_acc[n] = __builtin_amdgcn_mfma_f32_16x16x32_bf16(pa[1], vb1, o_acc[n], 0, 0, 0);
        }
        __builtin_amdgcn_s_setprio(0);
      }

      if (t + 1 < nt) SWRITE(cur ^ 1);   // next tile into other buffer
      __syncthreads();
      cur ^= 1;
    }

    // epilogue: O C-layout row q=4lk+r, col d=16n+qi
    float linv[4];
#pragma unroll
    for (int r = 0; r < 4; ++r) linv[r] = 1.0f / __shfl(l_run, 4 * lk + r, 64);
#pragma unroll
    for (int n = 0; n < 4; ++n)
#pragma unroll
      for (int r = 0; r < 4; ++r) {
        size_t row = bS + q0 + wid * 16 + 4 * lk + r;
        int col = h * HD_ + n * 16 + qi;
        O[row * D_MODEL + col] = f2bf(o_acc[n][r] * linv[r]);
      }
  }
}

// ---------------- launch ----------------
extern "C" void kernel_launch(void* const* d_in, const int* in_sizes, int n_in,
                              void* d_out, int out_size, void* d_ws, size_t ws_size,
                              hipStream_t stream) {
  const float* x  = (const float*)d_in[0];
  const float* fc = (const float*)d_in[1];
  const float* fs = (const float*)d_in[2];
  const float* wq = (const float*)d_in[3];
  const float* wk = (const float*)d_in[4];
  const float* wv = (const float*)d_in[5];
  const float* wo = (const float*)d_in[6];
  float* out = (float*)d_out;

  const size_t nx  = (size_t)BATCH * S_LEN * D_MODEL;
  const size_t nw  = (size_t)D_MODEL * D_MODEL;
  const size_t nwk = (size_t)KVD * D_MODEL;
  const size_t nkv = (size_t)BATCH * S_LEN * KVD;

  char* ws = (char*)d_ws;
  unsigned short* xb  = (unsigned short*)ws;  ws += nx  * 2;
  unsigned short* wqb = (unsigned short*)ws;  ws += nw  * 2;
  unsigned short* wkb = (unsigned short*)ws;  ws += nwk * 2;
  unsigned short* wvb = (unsigned short*)ws;  ws += nwk * 2;
  unsigned short* wob = (unsigned short*)ws;  ws += nw  * 2;
  unsigned short* qb  = (unsigned short*)ws;  ws += nx  * 2;
  unsigned short* kb  = (unsigned short*)ws;  ws += nkv * 2;
  unsigned short* vtb = (unsigned short*)ws;  ws += nkv * 2;   // V^T [KVD][MTOT]
  unsigned short* ab  = (unsigned short*)ws;  ws += nx  * 2;

  {
    int nx4 = nx / 4, na4 = nw / 4, nb4 = nwk / 4, nc4 = nwk / 4, nd4 = nw / 4;
    int tot = nx4 + na4 + nb4 + nc4 + nd4;
    cvt5_kernel<<<dim3((tot + 255) / 256), dim3(256), 0, stream>>>(x, wq, wk, wv, wo,
                                                                   xb, wqb, wkb, wvb, wob,
                                                                   nx4, na4, nb4, nc4, nd4);
  }

  const int M = BATCH * S_LEN;  // 4096
  gemm_qkv<<<dim3(768), dim3(256), 0, stream>>>(xb, wqb, wkb, wvb, fc, fs, qb, kb, vtb, M, D_MODEL);

  attn_kernel<<<dim3(8, BATCH * NH), dim3(512), 0, stream>>>(qb, kb, vtb, ab);

  gemm_out<<<dim3(512), dim3(256), 0, stream>>>(ab, wob, out, M, D_MODEL, D_MODEL);
}